// Round 6
// baseline (273.791 us; speedup 1.0000x reference)
//
#include <hip/hip_runtime.h>
#include <math.h>

#define N_NODES 50000
#define E_EDGES 800000
#define ET      (E_EDGES + N_NODES)   // edges + self loops
#define IN_DIM  128
#define HID     128
#define HEADS   8
#define C1      16
#define OUT_DIM 64
#define NEG_SLOPE 0.2f

#define TILE    8192
#define NT      ((ET + TILE - 1) / TILE)      // 104 tiles
#define NB      ((N_NODES + 255) / 256)       // 196 buckets of 256 nodes

typedef unsigned int uint32;
typedef __attribute__((ext_vector_type(8))) short bf16x8;
typedef __attribute__((ext_vector_type(4))) float f32x4;

static __device__ __forceinline__ unsigned short f2bf(float f) {
    uint32 u = __float_as_uint(f);
    u += 0x7FFFu + ((u >> 16) & 1u);   // round to nearest even
    return (unsigned short)(u >> 16);
}

// ---------------- CSR build: two-level bucket sort, no global atomics ----------------

__global__ __launch_bounds__(256) void bucket_hist(
        const int* __restrict__ dst, int* __restrict__ cnt /* [NB][NT] */) {
    __shared__ int hist[NB];
    int t = threadIdx.x;
    for (int b = t; b < NB; b += 256) hist[b] = 0;
    __syncthreads();
    int base = blockIdx.x * TILE;
    #pragma unroll
    for (int it = 0; it < TILE / 256; ++it) {
        int i = base + it * 256 + t;
        if (i < ET) {
            int d = (i < E_EDGES) ? dst[i] : (i - E_EDGES);
            atomicAdd(&hist[d >> 8], 1);
        }
    }
    __syncthreads();
    for (int b = t; b < NB; b += 256) cnt[b * NT + blockIdx.x] = hist[b];
}

__global__ __launch_bounds__(256) void bucket_scan(
        const int* __restrict__ cnt, int* __restrict__ tileOff /* [NB][NT] */,
        int* __restrict__ bucketStart /* [NB+1] */) {
    __shared__ int s[256];
    int t = threadIdx.x;
    int total = 0;
    if (t < NB) {
        int run = 0;
        for (int k = 0; k < NT; ++k) {
            int c = cnt[t * NT + k];
            tileOff[t * NT + k] = run;
            run += c;
        }
        total = run;
    }
    s[t] = total;
    __syncthreads();
    #pragma unroll
    for (int off = 1; off < 256; off <<= 1) {
        int add = (t >= off) ? s[t - off] : 0;
        __syncthreads();
        s[t] += add;
        __syncthreads();
    }
    if (t < NB) bucketStart[t] = s[t] - total;   // exclusive
    if (t == 0) bucketStart[NB] = ET;
}

__global__ __launch_bounds__(256) void bucket_scatter(
        const int* __restrict__ src, const int* __restrict__ dst,
        const int* __restrict__ tileOff, const int* __restrict__ bucketStart,
        int2* __restrict__ pairs) {
    __shared__ int cur[NB];
    int t = threadIdx.x;
    for (int b = t; b < NB; b += 256)
        cur[b] = bucketStart[b] + tileOff[b * NT + blockIdx.x];
    __syncthreads();
    int base = blockIdx.x * TILE;
    #pragma unroll
    for (int it = 0; it < TILE / 256; ++it) {
        int i = base + it * 256 + t;
        if (i < ET) {
            int s, d;
            if (i < E_EDGES) { s = src[i]; d = dst[i]; }
            else             { s = d = i - E_EDGES; }
            int pos = atomicAdd(&cur[d >> 8], 1);
            pairs[pos] = make_int2(s, d);
        }
    }
}

__global__ __launch_bounds__(256) void bucket_build(
        const int2* __restrict__ pairs, const int* __restrict__ bucketStart,
        int* __restrict__ row_start, int* __restrict__ csr_src) {
    __shared__ int sdeg[256];
    __shared__ int sscan[256];
    int t = threadIdx.x;
    int b = blockIdx.x;
    int beg = bucketStart[b], end = bucketStart[b + 1];
    sdeg[t] = 0;
    __syncthreads();
    for (int j = beg + t; j < end; j += 256)
        atomicAdd(&sdeg[pairs[j].y & 255], 1);
    __syncthreads();
    int v = sdeg[t];
    sscan[t] = v;
    __syncthreads();
    #pragma unroll
    for (int off = 1; off < 256; off <<= 1) {
        int add = (t >= off) ? sscan[t - off] : 0;
        __syncthreads();
        sscan[t] += add;
        __syncthreads();
    }
    int pos0 = beg + sscan[t] - v;   // exclusive prefix within bucket
    int n = b * 256 + t;
    if (n < N_NODES) row_start[n] = pos0;
    if (b == 0 && t == 0) row_start[N_NODES] = ET;
    __syncthreads();
    sscan[t] = pos0;                 // reuse as cursor
    __syncthreads();
    for (int j = beg + t; j < end; j += 256) {
        int2 p = pairs[j];
        int pos = atomicAdd(&sscan[p.y & 255], 1);
        csr_src[pos] = p.x;
    }
}

// ---------------- One-time operand prep ----------------

__global__ __launch_bounds__(256) void convert_x(
        const float* __restrict__ x, unsigned short* __restrict__ xb) {
    int i = blockIdx.x * blockDim.x + threadIdx.x;   // one float4 per thread
    const int total = N_NODES * IN_DIM / 4;
    if (i < total) {
        float4 v = ((const float4*)x)[i];
        ushort4 o;
        o.x = f2bf(v.x); o.y = f2bf(v.y); o.z = f2bf(v.z); o.w = f2bf(v.w);
        ((ushort4*)xb)[i] = o;
    }
}

// w1t[n][k] = bf16(W1[k][n]); p1t[j][k] = bf16( sum_c W1[k][c] * A[c][j] )
// where A[:,j<8] = as1 masked to head j, A[:,8+j] = ad1 masked to head j.
__global__ __launch_bounds__(128) void prep_w1(
        const float* __restrict__ W1, const float* __restrict__ as1,
        const float* __restrict__ ad1, unsigned short* __restrict__ w1t,
        unsigned short* __restrict__ p1t) {
    int k = threadIdx.x;   // 0..127
    for (int n = 0; n < HID; ++n)
        w1t[n * IN_DIM + k] = f2bf(W1[k * HID + n]);
    for (int j = 0; j < HEADS; ++j) {
        float s = 0.f, d = 0.f;
        #pragma unroll
        for (int c = 0; c < C1; ++c) {
            float w = W1[k * HID + j * C1 + c];
            s = fmaf(w, as1[j * C1 + c], s);
            d = fmaf(w, ad1[j * C1 + c], d);
        }
        p1t[j * IN_DIM + k] = f2bf(s);
        p1t[(8 + j) * IN_DIM + k] = f2bf(d);
    }
}

// w2t[n][k] = bf16(W2[k][n]); p2t[0][k] = sum_c W2[k][c]*as2[c]; p2t[1][k] = ...ad2; rows 2..15 = 0
__global__ __launch_bounds__(128) void prep_w2(
        const float* __restrict__ W2, const float* __restrict__ as2,
        const float* __restrict__ ad2, unsigned short* __restrict__ w2t,
        unsigned short* __restrict__ p2t) {
    int k = threadIdx.x;   // 0..127
    for (int n = 0; n < OUT_DIM; ++n)
        w2t[n * HID + k] = f2bf(W2[k * OUT_DIM + n]);
    float s = 0.f, d = 0.f;
    for (int c = 0; c < OUT_DIM; ++c) {
        float w = W2[k * OUT_DIM + c];
        s = fmaf(w, as2[c], s);
        d = fmaf(w, ad2[c], d);
    }
    p2t[0 * HID + k] = f2bf(s);
    p2t[1 * HID + k] = f2bf(d);
    for (int j = 2; j < 16; ++j) p2t[j * HID + k] = 0;
}

// ---------------- Layer 1: transform via MFMA, LDS-free ----------------
// 4 waves/block, wave = 16 nodes. A-frag A[m=lane&15][k=quad*8+j] straight from
// global bf16 xb; B-frag from transposed w1t (n-tile tt = head tt). Extra n-tile
// tt=8 multiplies by P1 -> cols 0..7 = a_src, 8..15 = a_dst (no shuffles).

__global__ __launch_bounds__(256) void l1_transform_mfma(
        const unsigned short* __restrict__ xb, const unsigned short* __restrict__ w1t,
        const unsigned short* __restrict__ p1t, unsigned short* __restrict__ h1b,
        float* __restrict__ a_src, float* __restrict__ a_dst) {
    int t = threadIdx.x, w = t >> 6, lane = t & 63;
    int l15 = lane & 15, quad = lane >> 4;
    int n0 = blockIdx.x * 64 + w * 16;
    int mrow = n0 + l15;
    int mload = (mrow < N_NODES) ? mrow : (N_NODES - 1);

    bf16x8 af[4];
    #pragma unroll
    for (int s = 0; s < 4; ++s)
        af[s] = *(const bf16x8*)&xb[(size_t)mload * IN_DIM + s * 32 + quad * 8];

    #pragma unroll
    for (int tt = 0; tt < 9; ++tt) {
        const unsigned short* Brow = (tt < 8) ? &w1t[(tt * 16 + l15) * IN_DIM]
                                              : &p1t[l15 * IN_DIM];
        f32x4 acc = {0.f, 0.f, 0.f, 0.f};
        #pragma unroll
        for (int s = 0; s < 4; ++s) {
            bf16x8 bf = *(const bf16x8*)&Brow[s * 32 + quad * 8];
            acc = __builtin_amdgcn_mfma_f32_16x16x32_bf16(af[s], bf, acc, 0, 0, 0);
        }
        int nodeb = n0 + quad * 4;
        if (tt < 8) {
            int ch = tt * 16 + l15;
            #pragma unroll
            for (int r = 0; r < 4; ++r)
                if (nodeb + r < N_NODES)
                    h1b[(size_t)(nodeb + r) * HID + ch] = f2bf(acc[r]);
        } else {
            #pragma unroll
            for (int r = 0; r < 4; ++r) {
                if (nodeb + r < N_NODES) {
                    if (l15 < 8) a_src[(nodeb + r) * HEADS + l15] = acc[r];
                    else         a_dst[(nodeb + r) * HEADS + (l15 - 8)] = acc[r];
                }
            }
        }
    }
}

// ---------------- Layer 1: aggregate (no-max softmax, bf16 out) ----------------

__global__ __launch_bounds__(128) void l1_aggregate(
        const unsigned short* __restrict__ h1b, const float* __restrict__ a_src,
        const float* __restrict__ a_dst, const int* __restrict__ row_start,
        const int* __restrict__ csr_src, const float* __restrict__ b1,
        unsigned short* __restrict__ h_act_b) {
    int w = threadIdx.x >> 6;
    int lane = threadIdx.x & 63;
    int n = blockIdx.x * 2 + w;
    int c0 = lane * 2;
    int h = lane >> 3;
    int beg = row_start[n], end = row_start[n + 1];
    float adst = a_dst[n * HEADS + h];
    float l = 0.f, accx = 0.f, accy = 0.f;

    auto update = [&](float e, uint32 u) {
        float vx = __uint_as_float(u << 16);
        float vy = __uint_as_float(u & 0xFFFF0000u);
        e += adst;
        e = fmaxf(e, NEG_SLOPE * e);          // leaky relu; |e| small -> exp safe
        float p = __expf(e);
        l += p;
        accx = fmaf(p, vx, accx);
        accy = fmaf(p, vy, accy);
    };

    int j = beg;
    for (; j + 4 <= end; j += 4) {
        int s0 = csr_src[j + 0], s1 = csr_src[j + 1];
        int s2 = csr_src[j + 2], s3 = csr_src[j + 3];
        float e0 = a_src[s0 * HEADS + h];
        float e1 = a_src[s1 * HEADS + h];
        float e2 = a_src[s2 * HEADS + h];
        float e3 = a_src[s3 * HEADS + h];
        uint32 u0 = *(const uint32*)&h1b[(size_t)s0 * HID + c0];
        uint32 u1 = *(const uint32*)&h1b[(size_t)s1 * HID + c0];
        uint32 u2 = *(const uint32*)&h1b[(size_t)s2 * HID + c0];
        uint32 u3 = *(const uint32*)&h1b[(size_t)s3 * HID + c0];
        update(e0, u0); update(e1, u1); update(e2, u2); update(e3, u3);
    }
    for (; j < end; ++j) {
        int s = csr_src[j];
        float e = a_src[s * HEADS + h];
        uint32 u = *(const uint32*)&h1b[(size_t)s * HID + c0];
        update(e, u);
    }

    float inv = 1.f / (l + 1e-16f);
    float vx = accx * inv + b1[c0];
    float vy = accy * inv + b1[c0 + 1];
    vx = vx > 0.f ? vx : (__expf(vx) - 1.f);   // ELU
    vy = vy > 0.f ? vy : (__expf(vy) - 1.f);
    uint32 packed = (uint32)f2bf(vx) | ((uint32)f2bf(vy) << 16);
    *(uint32*)&h_act_b[(size_t)n * HID + c0] = packed;
}

// ---------------- Layer 2: transform via MFMA, LDS-free ----------------
// tt 0..3 = output channels; tt=4 multiplies by P2 -> col 0 = a_src2, col 1 = a_dst2.

__global__ __launch_bounds__(256) void l2_transform_mfma(
        const unsigned short* __restrict__ h_act_b, const unsigned short* __restrict__ w2t,
        const unsigned short* __restrict__ p2t, unsigned short* __restrict__ h2b,
        float* __restrict__ a_src2, float* __restrict__ a_dst2) {
    int t = threadIdx.x, w = t >> 6, lane = t & 63;
    int l15 = lane & 15, quad = lane >> 4;
    int n0 = blockIdx.x * 64 + w * 16;
    int mrow = n0 + l15;
    int mload = (mrow < N_NODES) ? mrow : (N_NODES - 1);

    bf16x8 af[4];
    #pragma unroll
    for (int s = 0; s < 4; ++s)
        af[s] = *(const bf16x8*)&h_act_b[(size_t)mload * HID + s * 32 + quad * 8];

    #pragma unroll
    for (int tt = 0; tt < 5; ++tt) {
        const unsigned short* Brow = (tt < 4) ? &w2t[(tt * 16 + l15) * HID]
                                              : &p2t[l15 * HID];
        f32x4 acc = {0.f, 0.f, 0.f, 0.f};
        #pragma unroll
        for (int s = 0; s < 4; ++s) {
            bf16x8 bf = *(const bf16x8*)&Brow[s * 32 + quad * 8];
            acc = __builtin_amdgcn_mfma_f32_16x16x32_bf16(af[s], bf, acc, 0, 0, 0);
        }
        int nodeb = n0 + quad * 4;
        if (tt < 4) {
            int ch = tt * 16 + l15;
            #pragma unroll
            for (int r = 0; r < 4; ++r)
                if (nodeb + r < N_NODES)
                    h2b[(size_t)(nodeb + r) * OUT_DIM + ch] = f2bf(acc[r]);
        } else {
            #pragma unroll
            for (int r = 0; r < 4; ++r) {
                if (nodeb + r < N_NODES) {
                    if (l15 == 0) a_src2[nodeb + r] = acc[r];
                    else if (l15 == 1) a_dst2[nodeb + r] = acc[r];
                }
            }
        }
    }
}

// ---------------- Layer 2: aggregate + log_softmax ----------------

__global__ __launch_bounds__(128) void l2_aggregate(
        const unsigned short* __restrict__ h2b, const float* __restrict__ a_src2,
        const float* __restrict__ a_dst2, const int* __restrict__ row_start,
        const int* __restrict__ csr_src, const float* __restrict__ b2,
        float* __restrict__ out) {
    int w = threadIdx.x >> 6;
    int lane = threadIdx.x & 63;
    int n = blockIdx.x * 2 + w;
    int beg = row_start[n], end = row_start[n + 1];
    float adst = a_dst2[n];
    float l = 0.f, acc = 0.f;

    auto update = [&](float e, unsigned short us) {
        float v = __uint_as_float(((uint32)us) << 16);
        e += adst;
        e = fmaxf(e, NEG_SLOPE * e);
        float p = __expf(e);
        l += p;
        acc = fmaf(p, v, acc);
    };

    int j = beg;
    for (; j + 4 <= end; j += 4) {
        int s0 = csr_src[j + 0], s1 = csr_src[j + 1];
        int s2 = csr_src[j + 2], s3 = csr_src[j + 3];
        float e0 = a_src2[s0], e1 = a_src2[s1];
        float e2 = a_src2[s2], e3 = a_src2[s3];
        unsigned short v0 = h2b[(size_t)s0 * OUT_DIM + lane];
        unsigned short v1 = h2b[(size_t)s1 * OUT_DIM + lane];
        unsigned short v2 = h2b[(size_t)s2 * OUT_DIM + lane];
        unsigned short v3 = h2b[(size_t)s3 * OUT_DIM + lane];
        update(e0, v0); update(e1, v1); update(e2, v2); update(e3, v3);
    }
    for (; j < end; ++j) {
        int s = csr_src[j];
        update(a_src2[s], h2b[(size_t)s * OUT_DIM + lane]);
    }

    float o = acc / (l + 1e-16f) + b2[lane];
    // log_softmax over 64 channels (one wave)
    float mx = o;
    #pragma unroll
    for (int ww = 32; ww > 0; ww >>= 1) mx = fmaxf(mx, __shfl_xor(mx, ww, 64));
    float ex = __expf(o - mx);
    float ssum = ex;
    #pragma unroll
    for (int ww = 32; ww > 0; ww >>= 1) ssum += __shfl_xor(ssum, ww, 64);
    out[(size_t)n * OUT_DIM + lane] = o - mx - __logf(ssum);
}

// ---------------- launch ----------------

extern "C" void kernel_launch(void* const* d_in, const int* in_sizes, int n_in,
                              void* d_out, int out_size, void* d_ws, size_t ws_size,
                              hipStream_t stream) {
    const float* x   = (const float*)d_in[0];
    const int*   ei  = (const int*)d_in[1];
    const float* W1  = (const float*)d_in[2];
    const float* as1 = (const float*)d_in[3];
    const float* ad1 = (const float*)d_in[4];
    const float* b1  = (const float*)d_in[5];
    const float* W2  = (const float*)d_in[6];
    const float* as2 = (const float*)d_in[7];
    const float* ad2 = (const float*)d_in[8];
    const float* b2  = (const float*)d_in[9];
    float* out = (float*)d_out;

    const int* src = ei;             // row 0
    const int* dst = ei + E_EDGES;   // row 1

    char* ws = (char*)d_ws;
    size_t off = 0;
    auto alloc = [&](size_t bytes) -> void* {
        void* p = ws + off;
        off += (bytes + 255) & ~size_t(255);
        return p;
    };
    unsigned short* xb     = (unsigned short*)alloc((size_t)N_NODES * IN_DIM * 2);
    unsigned short* h1b    = (unsigned short*)alloc((size_t)N_NODES * HID * 2);
    unsigned short* h_act_b= (unsigned short*)alloc((size_t)N_NODES * HID * 2);
    unsigned short* h2b    = (unsigned short*)alloc((size_t)N_NODES * OUT_DIM * 2);
    unsigned short* w1t    = (unsigned short*)alloc((size_t)HID * IN_DIM * 2);
    unsigned short* p1t    = (unsigned short*)alloc((size_t)16 * IN_DIM * 2);
    unsigned short* w2t    = (unsigned short*)alloc((size_t)OUT_DIM * HID * 2);
    unsigned short* p2t    = (unsigned short*)alloc((size_t)16 * HID * 2);
    float* a_src1    = (float*)alloc((size_t)N_NODES * HEADS * 4);
    float* a_dst1    = (float*)alloc((size_t)N_NODES * HEADS * 4);
    float* a_src2    = (float*)alloc((size_t)N_NODES * 4);
    float* a_dst2    = (float*)alloc((size_t)N_NODES * 4);
    int*   row_start = (int*)alloc((size_t)(N_NODES + 1) * 4);
    int*   csr_src   = (int*)alloc((size_t)ET * 4);
    int2*  pairs     = (int2*)alloc((size_t)ET * 8);
    int*   cnt       = (int*)alloc((size_t)NB * NT * 4);
    int*   tileOff   = (int*)alloc((size_t)NB * NT * 4);
    int*   bucketStart = (int*)alloc((size_t)(NB + 1) * 4);

    // CSR build
    bucket_hist<<<NT, 256, 0, stream>>>(dst, cnt);
    bucket_scan<<<1, 256, 0, stream>>>(cnt, tileOff, bucketStart);
    bucket_scatter<<<NT, 256, 0, stream>>>(src, dst, tileOff, bucketStart, pairs);
    bucket_build<<<NB, 256, 0, stream>>>(pairs, bucketStart, row_start, csr_src);

    // operand prep
    convert_x<<<(N_NODES * IN_DIM / 4 + 255) / 256, 256, 0, stream>>>(x, xb);
    prep_w1<<<1, 128, 0, stream>>>(W1, as1, ad1, w1t, p1t);
    prep_w2<<<1, 128, 0, stream>>>(W2, as2, ad2, w2t, p2t);

    int tb = (N_NODES + 63) / 64;   // 782
    l1_transform_mfma<<<tb, 256, 0, stream>>>(xb, w1t, p1t, h1b, a_src1, a_dst1);
    l1_aggregate<<<N_NODES / 2, 128, 0, stream>>>(h1b, a_src1, a_dst1, row_start, csr_src, b1, h_act_b);
    l2_transform_mfma<<<tb, 256, 0, stream>>>(h_act_b, w2t, p2t, h2b, a_src2, a_dst2);
    l2_aggregate<<<N_NODES / 2, 128, 0, stream>>>(h2b, a_src2, a_dst2, row_start, csr_src, b2, out);
}

// Round 7
// 259.103 us; speedup vs baseline: 1.0567x; 1.0567x over previous
//
#include <hip/hip_runtime.h>
#include <math.h>

#define N_NODES 50000
#define E_EDGES 800000
#define ET      (E_EDGES + N_NODES)   // edges + self loops
#define IN_DIM  128
#define HID     128
#define HEADS   8
#define C1      16
#define OUT_DIM 64
#define NEG_SLOPE 0.2f

#define TILE    8192
#define NT      ((ET + TILE - 1) / TILE)      // 104 tiles
#define NB      ((N_NODES + 255) / 256)       // 196 buckets of 256 nodes

typedef unsigned int uint32;
typedef __attribute__((ext_vector_type(8))) short bf16x8;
typedef __attribute__((ext_vector_type(4))) float f32x4;

static __device__ __forceinline__ unsigned short f2bf(float f) {
    uint32 u = __float_as_uint(f);
    u += 0x7FFFu + ((u >> 16) & 1u);   // round to nearest even
    return (unsigned short)(u >> 16);
}

// ---------------- CSR build: two-level bucket sort, no global atomics ----------------
// cnt/tileOff layout is [NT][NB] so bucket_scan reads coalesced across lanes.

__global__ __launch_bounds__(256) void bucket_hist(
        const int* __restrict__ dst, int* __restrict__ cnt /* [NT][NB] */) {
    __shared__ int hist[NB];
    int t = threadIdx.x;
    for (int b = t; b < NB; b += 256) hist[b] = 0;
    __syncthreads();
    int base = blockIdx.x * TILE;
    #pragma unroll
    for (int it = 0; it < TILE / 256; ++it) {
        int i = base + it * 256 + t;
        if (i < ET) {
            int d = (i < E_EDGES) ? dst[i] : (i - E_EDGES);
            atomicAdd(&hist[d >> 8], 1);
        }
    }
    __syncthreads();
    for (int b = t; b < NB; b += 256) cnt[blockIdx.x * NB + b] = hist[b];
}

__global__ __launch_bounds__(256) void bucket_scan(
        const int* __restrict__ cnt, int* __restrict__ tileOff /* [NT][NB] */,
        int* __restrict__ bucketStart /* [NB+1] */) {
    __shared__ int s[256];
    int t = threadIdx.x;
    int total = 0;
    if (t < NB) {
        int run = 0;
        for (int k = 0; k < NT; ++k) {
            int c = cnt[k * NB + t];       // coalesced across t
            tileOff[k * NB + t] = run;
            run += c;
        }
        total = run;
    }
    s[t] = total;
    __syncthreads();
    #pragma unroll
    for (int off = 1; off < 256; off <<= 1) {
        int add = (t >= off) ? s[t - off] : 0;
        __syncthreads();
        s[t] += add;
        __syncthreads();
    }
    if (t < NB) bucketStart[t] = s[t] - total;   // exclusive
    if (t == 0) bucketStart[NB] = ET;
}

__global__ __launch_bounds__(256) void bucket_scatter(
        const int* __restrict__ src, const int* __restrict__ dst,
        const int* __restrict__ tileOff, const int* __restrict__ bucketStart,
        int2* __restrict__ pairs) {
    __shared__ int cur[NB];
    int t = threadIdx.x;
    for (int b = t; b < NB; b += 256)
        cur[b] = bucketStart[b] + tileOff[blockIdx.x * NB + b];
    __syncthreads();
    int base = blockIdx.x * TILE;
    #pragma unroll
    for (int it = 0; it < TILE / 256; ++it) {
        int i = base + it * 256 + t;
        if (i < ET) {
            int s, d;
            if (i < E_EDGES) { s = src[i]; d = dst[i]; }
            else             { s = d = i - E_EDGES; }
            int pos = atomicAdd(&cur[d >> 8], 1);
            pairs[pos] = make_int2(s, d);
        }
    }
}

__global__ __launch_bounds__(256) void bucket_build(
        const int2* __restrict__ pairs, const int* __restrict__ bucketStart,
        int* __restrict__ row_start, int* __restrict__ csr_src) {
    __shared__ int sdeg[256];
    __shared__ int sscan[256];
    int t = threadIdx.x;
    int b = blockIdx.x;
    int beg = bucketStart[b], end = bucketStart[b + 1];
    sdeg[t] = 0;
    __syncthreads();
    for (int j = beg + t; j < end; j += 256)
        atomicAdd(&sdeg[pairs[j].y & 255], 1);
    __syncthreads();
    int v = sdeg[t];
    sscan[t] = v;
    __syncthreads();
    #pragma unroll
    for (int off = 1; off < 256; off <<= 1) {
        int add = (t >= off) ? sscan[t - off] : 0;
        __syncthreads();
        sscan[t] += add;
        __syncthreads();
    }
    int pos0 = beg + sscan[t] - v;   // exclusive prefix within bucket
    int n = b * 256 + t;
    if (n < N_NODES) row_start[n] = pos0;
    if (b == 0 && t == 0) row_start[N_NODES] = ET;
    __syncthreads();
    sscan[t] = pos0;                 // reuse as cursor
    __syncthreads();
    for (int j = beg + t; j < end; j += 256) {
        int2 p = pairs[j];
        int pos = atomicAdd(&sscan[p.y & 255], 1);
        csr_src[pos] = p.x;
    }
}

// ---------------- One-time operand prep ----------------

__global__ __launch_bounds__(256) void convert_x(
        const float* __restrict__ x, unsigned short* __restrict__ xb) {
    int i = blockIdx.x * blockDim.x + threadIdx.x;   // one float4 per thread
    const int total = N_NODES * IN_DIM / 4;
    if (i < total) {
        float4 v = ((const float4*)x)[i];
        ushort4 o;
        o.x = f2bf(v.x); o.y = f2bf(v.y); o.z = f2bf(v.z); o.w = f2bf(v.w);
        ((ushort4*)xb)[i] = o;
    }
}

// One parallel kernel for all weight prep (112 blocks):
//  blocks [0,64):   w1t[n][k] = bf16(W1[k][n])          (16384 elems)
//  blocks [64,96):  w2t[n][k] = bf16(W2[k][n])          (8192 elems)
//  blocks [96,104): p1t[j][k] = bf16(sum_c W1[k][hC1+c]*a1[hC1+c]), j<8 src else dst
//  blocks [104,112): p2t[j][k]: j=0 src-dot, j=1 dst-dot, j>=2 zero
__global__ __launch_bounds__(256) void prep_weights(
        const float* __restrict__ W1, const float* __restrict__ as1,
        const float* __restrict__ ad1, const float* __restrict__ W2,
        const float* __restrict__ as2, const float* __restrict__ ad2,
        unsigned short* __restrict__ w1t, unsigned short* __restrict__ p1t,
        unsigned short* __restrict__ w2t, unsigned short* __restrict__ p2t) {
    int b = blockIdx.x, t = threadIdx.x;
    if (b < 64) {
        int i = b * 256 + t;                // n*128+k
        int n = i >> 7, k = i & 127;
        w1t[n * IN_DIM + k] = f2bf(W1[k * HID + n]);
    } else if (b < 96) {
        int i = (b - 64) * 256 + t;         // n*128+k, n<64
        int n = i >> 7, k = i & 127;
        w2t[n * HID + k] = f2bf(W2[k * OUT_DIM + n]);
    } else if (b < 104) {
        int i = (b - 96) * 256 + t;         // j*128+k, j<16
        int j = i >> 7, k = i & 127;
        int hh = j & 7;
        const float* a = (j < 8) ? as1 : ad1;
        float acc = 0.f;
        #pragma unroll
        for (int c = 0; c < C1; ++c)
            acc = fmaf(W1[k * HID + hh * C1 + c], a[hh * C1 + c], acc);
        p1t[j * IN_DIM + k] = f2bf(acc);
    } else {
        int i = (b - 104) * 256 + t;        // j*128+k, j<16
        int j = i >> 7, k = i & 127;
        if (j < 2) {
            const float* a = (j == 0) ? as2 : ad2;
            float acc = 0.f;
            #pragma unroll
            for (int c = 0; c < OUT_DIM; ++c)
                acc = fmaf(W2[k * OUT_DIM + c], a[c], acc);
            p2t[j * HID + k] = f2bf(acc);
        } else {
            p2t[j * HID + k] = 0;
        }
    }
}

// ---------------- Layer 1: transform via MFMA, LDS-free ----------------
// 4 waves/block, wave = 16 nodes. A-frag A[m=lane&15][k=quad*8+j] straight from
// global bf16 xb; B-frag from transposed w1t (n-tile tt = head tt). Extra n-tile
// tt=8 multiplies by P1 -> cols 0..7 = a_src, 8..15 = a_dst (no shuffles).

__global__ __launch_bounds__(256) void l1_transform_mfma(
        const unsigned short* __restrict__ xb, const unsigned short* __restrict__ w1t,
        const unsigned short* __restrict__ p1t, unsigned short* __restrict__ h1b,
        float* __restrict__ a_src, float* __restrict__ a_dst) {
    int t = threadIdx.x, w = t >> 6, lane = t & 63;
    int l15 = lane & 15, quad = lane >> 4;
    int n0 = blockIdx.x * 64 + w * 16;
    int mrow = n0 + l15;
    int mload = (mrow < N_NODES) ? mrow : (N_NODES - 1);

    bf16x8 af[4];
    #pragma unroll
    for (int s = 0; s < 4; ++s)
        af[s] = *(const bf16x8*)&xb[(size_t)mload * IN_DIM + s * 32 + quad * 8];

    #pragma unroll
    for (int tt = 0; tt < 9; ++tt) {
        const unsigned short* Brow = (tt < 8) ? &w1t[(tt * 16 + l15) * IN_DIM]
                                              : &p1t[l15 * IN_DIM];
        f32x4 acc = {0.f, 0.f, 0.f, 0.f};
        #pragma unroll
        for (int s = 0; s < 4; ++s) {
            bf16x8 bf = *(const bf16x8*)&Brow[s * 32 + quad * 8];
            acc = __builtin_amdgcn_mfma_f32_16x16x32_bf16(af[s], bf, acc, 0, 0, 0);
        }
        int nodeb = n0 + quad * 4;
        if (tt < 8) {
            int ch = tt * 16 + l15;
            #pragma unroll
            for (int r = 0; r < 4; ++r)
                if (nodeb + r < N_NODES)
                    h1b[(size_t)(nodeb + r) * HID + ch] = f2bf(acc[r]);
        } else {
            #pragma unroll
            for (int r = 0; r < 4; ++r) {
                if (nodeb + r < N_NODES) {
                    if (l15 < 8) a_src[(nodeb + r) * HEADS + l15] = acc[r];
                    else         a_dst[(nodeb + r) * HEADS + (l15 - 8)] = acc[r];
                }
            }
        }
    }
}

// ---------------- Layer 1: aggregate (no-max softmax, bf16 out) ----------------

__global__ __launch_bounds__(128) void l1_aggregate(
        const unsigned short* __restrict__ h1b, const float* __restrict__ a_src,
        const float* __restrict__ a_dst, const int* __restrict__ row_start,
        const int* __restrict__ csr_src, const float* __restrict__ b1,
        unsigned short* __restrict__ h_act_b) {
    int w = threadIdx.x >> 6;
    int lane = threadIdx.x & 63;
    int n = blockIdx.x * 2 + w;
    int c0 = lane * 2;
    int h = lane >> 3;
    int beg = row_start[n], end = row_start[n + 1];
    float adst = a_dst[n * HEADS + h];
    float l = 0.f, accx = 0.f, accy = 0.f;

    auto update = [&](float e, uint32 u) {
        float vx = __uint_as_float(u << 16);
        float vy = __uint_as_float(u & 0xFFFF0000u);
        e += adst;
        e = fmaxf(e, NEG_SLOPE * e);          // leaky relu; |e| small -> exp safe
        float p = __expf(e);
        l += p;
        accx = fmaf(p, vx, accx);
        accy = fmaf(p, vy, accy);
    };

    int j = beg;
    for (; j + 4 <= end; j += 4) {
        int s0 = csr_src[j + 0], s1 = csr_src[j + 1];
        int s2 = csr_src[j + 2], s3 = csr_src[j + 3];
        float e0 = a_src[s0 * HEADS + h];
        float e1 = a_src[s1 * HEADS + h];
        float e2 = a_src[s2 * HEADS + h];
        float e3 = a_src[s3 * HEADS + h];
        uint32 u0 = *(const uint32*)&h1b[(size_t)s0 * HID + c0];
        uint32 u1 = *(const uint32*)&h1b[(size_t)s1 * HID + c0];
        uint32 u2 = *(const uint32*)&h1b[(size_t)s2 * HID + c0];
        uint32 u3 = *(const uint32*)&h1b[(size_t)s3 * HID + c0];
        update(e0, u0); update(e1, u1); update(e2, u2); update(e3, u3);
    }
    for (; j < end; ++j) {
        int s = csr_src[j];
        float e = a_src[s * HEADS + h];
        uint32 u = *(const uint32*)&h1b[(size_t)s * HID + c0];
        update(e, u);
    }

    float inv = 1.f / (l + 1e-16f);
    float vx = accx * inv + b1[c0];
    float vy = accy * inv + b1[c0 + 1];
    vx = vx > 0.f ? vx : (__expf(vx) - 1.f);   // ELU
    vy = vy > 0.f ? vy : (__expf(vy) - 1.f);
    uint32 packed = (uint32)f2bf(vx) | ((uint32)f2bf(vy) << 16);
    *(uint32*)&h_act_b[(size_t)n * HID + c0] = packed;
}

// ---------------- Layer 2: transform via MFMA, LDS-free ----------------
// tt 0..3 = output channels; tt=4 multiplies by P2 -> col 0 = a_src2, col 1 = a_dst2.

__global__ __launch_bounds__(256) void l2_transform_mfma(
        const unsigned short* __restrict__ h_act_b, const unsigned short* __restrict__ w2t,
        const unsigned short* __restrict__ p2t, unsigned short* __restrict__ h2b,
        float* __restrict__ a_src2, float* __restrict__ a_dst2) {
    int t = threadIdx.x, w = t >> 6, lane = t & 63;
    int l15 = lane & 15, quad = lane >> 4;
    int n0 = blockIdx.x * 64 + w * 16;
    int mrow = n0 + l15;
    int mload = (mrow < N_NODES) ? mrow : (N_NODES - 1);

    bf16x8 af[4];
    #pragma unroll
    for (int s = 0; s < 4; ++s)
        af[s] = *(const bf16x8*)&h_act_b[(size_t)mload * HID + s * 32 + quad * 8];

    #pragma unroll
    for (int tt = 0; tt < 5; ++tt) {
        const unsigned short* Brow = (tt < 4) ? &w2t[(tt * 16 + l15) * HID]
                                              : &p2t[l15 * HID];
        f32x4 acc = {0.f, 0.f, 0.f, 0.f};
        #pragma unroll
        for (int s = 0; s < 4; ++s) {
            bf16x8 bf = *(const bf16x8*)&Brow[s * 32 + quad * 8];
            acc = __builtin_amdgcn_mfma_f32_16x16x32_bf16(af[s], bf, acc, 0, 0, 0);
        }
        int nodeb = n0 + quad * 4;
        if (tt < 4) {
            int ch = tt * 16 + l15;
            #pragma unroll
            for (int r = 0; r < 4; ++r)
                if (nodeb + r < N_NODES)
                    h2b[(size_t)(nodeb + r) * OUT_DIM + ch] = f2bf(acc[r]);
        } else {
            #pragma unroll
            for (int r = 0; r < 4; ++r) {
                if (nodeb + r < N_NODES) {
                    if (l15 == 0) a_src2[nodeb + r] = acc[r];
                    else if (l15 == 1) a_dst2[nodeb + r] = acc[r];
                }
            }
        }
    }
}

// ---------------- Layer 2: aggregate + log_softmax ----------------

__global__ __launch_bounds__(128) void l2_aggregate(
        const unsigned short* __restrict__ h2b, const float* __restrict__ a_src2,
        const float* __restrict__ a_dst2, const int* __restrict__ row_start,
        const int* __restrict__ csr_src, const float* __restrict__ b2,
        float* __restrict__ out) {
    int w = threadIdx.x >> 6;
    int lane = threadIdx.x & 63;
    int n = blockIdx.x * 2 + w;
    int beg = row_start[n], end = row_start[n + 1];
    float adst = a_dst2[n];
    float l = 0.f, acc = 0.f;

    auto update = [&](float e, unsigned short us) {
        float v = __uint_as_float(((uint32)us) << 16);
        e += adst;
        e = fmaxf(e, NEG_SLOPE * e);
        float p = __expf(e);
        l += p;
        acc = fmaf(p, v, acc);
    };

    int j = beg;
    for (; j + 4 <= end; j += 4) {
        int s0 = csr_src[j + 0], s1 = csr_src[j + 1];
        int s2 = csr_src[j + 2], s3 = csr_src[j + 3];
        float e0 = a_src2[s0], e1 = a_src2[s1];
        float e2 = a_src2[s2], e3 = a_src2[s3];
        unsigned short v0 = h2b[(size_t)s0 * OUT_DIM + lane];
        unsigned short v1 = h2b[(size_t)s1 * OUT_DIM + lane];
        unsigned short v2 = h2b[(size_t)s2 * OUT_DIM + lane];
        unsigned short v3 = h2b[(size_t)s3 * OUT_DIM + lane];
        update(e0, v0); update(e1, v1); update(e2, v2); update(e3, v3);
    }
    for (; j < end; ++j) {
        int s = csr_src[j];
        update(a_src2[s], h2b[(size_t)s * OUT_DIM + lane]);
    }

    float o = acc / (l + 1e-16f) + b2[lane];
    // log_softmax over 64 channels (one wave)
    float mx = o;
    #pragma unroll
    for (int ww = 32; ww > 0; ww >>= 1) mx = fmaxf(mx, __shfl_xor(mx, ww, 64));
    float ex = __expf(o - mx);
    float ssum = ex;
    #pragma unroll
    for (int ww = 32; ww > 0; ww >>= 1) ssum += __shfl_xor(ssum, ww, 64);
    out[(size_t)n * OUT_DIM + lane] = o - mx - __logf(ssum);
}

// ---------------- launch ----------------

extern "C" void kernel_launch(void* const* d_in, const int* in_sizes, int n_in,
                              void* d_out, int out_size, void* d_ws, size_t ws_size,
                              hipStream_t stream) {
    const float* x   = (const float*)d_in[0];
    const int*   ei  = (const int*)d_in[1];
    const float* W1  = (const float*)d_in[2];
    const float* as1 = (const float*)d_in[3];
    const float* ad1 = (const float*)d_in[4];
    const float* b1  = (const float*)d_in[5];
    const float* W2  = (const float*)d_in[6];
    const float* as2 = (const float*)d_in[7];
    const float* ad2 = (const float*)d_in[8];
    const float* b2  = (const float*)d_in[9];
    float* out = (float*)d_out;

    const int* src = ei;             // row 0
    const int* dst = ei + E_EDGES;   // row 1

    char* ws = (char*)d_ws;
    size_t off = 0;
    auto alloc = [&](size_t bytes) -> void* {
        void* p = ws + off;
        off += (bytes + 255) & ~size_t(255);
        return p;
    };
    unsigned short* xb     = (unsigned short*)alloc((size_t)N_NODES * IN_DIM * 2);
    unsigned short* h1b    = (unsigned short*)alloc((size_t)N_NODES * HID * 2);
    unsigned short* h_act_b= (unsigned short*)alloc((size_t)N_NODES * HID * 2);
    unsigned short* h2b    = (unsigned short*)alloc((size_t)N_NODES * OUT_DIM * 2);
    unsigned short* w1t    = (unsigned short*)alloc((size_t)HID * IN_DIM * 2);
    unsigned short* p1t    = (unsigned short*)alloc((size_t)16 * IN_DIM * 2);
    unsigned short* w2t    = (unsigned short*)alloc((size_t)OUT_DIM * HID * 2);
    unsigned short* p2t    = (unsigned short*)alloc((size_t)16 * HID * 2);
    float* a_src1    = (float*)alloc((size_t)N_NODES * HEADS * 4);
    float* a_dst1    = (float*)alloc((size_t)N_NODES * HEADS * 4);
    float* a_src2    = (float*)alloc((size_t)N_NODES * 4);
    float* a_dst2    = (float*)alloc((size_t)N_NODES * 4);
    int*   row_start = (int*)alloc((size_t)(N_NODES + 1) * 4);
    int*   csr_src   = (int*)alloc((size_t)ET * 4);
    int2*  pairs     = (int2*)alloc((size_t)ET * 8);
    int*   cnt       = (int*)alloc((size_t)NB * NT * 4);
    int*   tileOff   = (int*)alloc((size_t)NB * NT * 4);
    int*   bucketStart = (int*)alloc((size_t)(NB + 1) * 4);

    // CSR build
    bucket_hist<<<NT, 256, 0, stream>>>(dst, cnt);
    bucket_scan<<<1, 256, 0, stream>>>(cnt, tileOff, bucketStart);
    bucket_scatter<<<NT, 256, 0, stream>>>(src, dst, tileOff, bucketStart, pairs);
    bucket_build<<<NB, 256, 0, stream>>>(pairs, bucketStart, row_start, csr_src);

    // operand prep (parallel)
    convert_x<<<(N_NODES * IN_DIM / 4 + 255) / 256, 256, 0, stream>>>(x, xb);
    prep_weights<<<112, 256, 0, stream>>>(W1, as1, ad1, W2, as2, ad2, w1t, p1t, w2t, p2t);

    int tb = (N_NODES + 63) / 64;   // 782
    l1_transform_mfma<<<tb, 256, 0, stream>>>(xb, w1t, p1t, h1b, a_src1, a_dst1);
    l1_aggregate<<<N_NODES / 2, 128, 0, stream>>>(h1b, a_src1, a_dst1, row_start, csr_src, b1, h_act_b);
    l2_transform_mfma<<<tb, 256, 0, stream>>>(h_act_b, w2t, p2t, h2b, a_src2, a_dst2);
    l2_aggregate<<<N_NODES / 2, 128, 0, stream>>>(h2b, a_src2, a_dst2, row_start, csr_src, b2, out);
}

// Round 8
// 232.735 us; speedup vs baseline: 1.1764x; 1.1133x over previous
//
#include <hip/hip_runtime.h>
#include <math.h>

#define N_NODES 50000
#define E_EDGES 800000
#define ET      (E_EDGES + N_NODES)   // edges + self loops
#define IN_DIM  128
#define HID     128
#define HEADS   8
#define C1      16
#define OUT_DIM 64
#define NEG_SLOPE 0.2f
#define LOG2E   1.4426950408889634f

#define TILE    8192
#define NT      ((ET + TILE - 1) / TILE)      // 104 tiles
#define NB      ((N_NODES + 255) / 256)       // 196 buckets of 256 nodes

#define CONV_BLOCKS (N_NODES * IN_DIM / 4 / 256)   // 6250
#define PREP_BLOCKS 112
#define MEGA_A (NT + CONV_BLOCKS + PREP_BLOCKS)    // 6466
#define L1T_BLOCKS ((N_NODES + 63) / 64)           // 782
#define MEGA_B (NB + L1T_BLOCKS)                   // 978

typedef unsigned int uint32;
typedef __attribute__((ext_vector_type(8))) short bf16x8;
typedef __attribute__((ext_vector_type(4))) float f32x4;

static __device__ __forceinline__ unsigned short f2bf(float f) {
    uint32 u = __float_as_uint(f);
    u += 0x7FFFu + ((u >> 16) & 1u);   // round to nearest even
    return (unsigned short)(u >> 16);
}

// ---------------- Mega-kernel A: bucket_hist + convert_x + prep_weights ----------------
// cnt layout [NT][NB] so bucket_scan reads coalesced across lanes.
// p1t/p2t rows are pre-scaled by log2(e) so aggregates use bare exp2f.

__global__ __launch_bounds__(256) void prep_all(
        const int* __restrict__ dst, int* __restrict__ cnt,
        const float* __restrict__ x, unsigned short* __restrict__ xb,
        const float* __restrict__ W1, const float* __restrict__ as1,
        const float* __restrict__ ad1, const float* __restrict__ W2,
        const float* __restrict__ as2, const float* __restrict__ ad2,
        unsigned short* __restrict__ w1t, unsigned short* __restrict__ p1t,
        unsigned short* __restrict__ w2t, unsigned short* __restrict__ p2t) {
    __shared__ int hist[NB];
    int blk = blockIdx.x, t = threadIdx.x;
    if (blk < NT) {
        // ---- bucket histogram over one edge tile ----
        for (int b = t; b < NB; b += 256) hist[b] = 0;
        __syncthreads();
        int base = blk * TILE;
        #pragma unroll
        for (int it = 0; it < TILE / 256; ++it) {
            int i = base + it * 256 + t;
            if (i < ET) {
                int d = (i < E_EDGES) ? dst[i] : (i - E_EDGES);
                atomicAdd(&hist[d >> 8], 1);
            }
        }
        __syncthreads();
        for (int b = t; b < NB; b += 256) cnt[blk * NB + b] = hist[b];
    } else if (blk < NT + CONV_BLOCKS) {
        // ---- x -> bf16 ----
        int i = (blk - NT) * 256 + t;
        float4 v = ((const float4*)x)[i];
        ushort4 o;
        o.x = f2bf(v.x); o.y = f2bf(v.y); o.z = f2bf(v.z); o.w = f2bf(v.w);
        ((ushort4*)xb)[i] = o;
    } else {
        int b = blk - NT - CONV_BLOCKS;    // 0..111
        if (b < 64) {
            int i = b * 256 + t;                // n*128+k
            int n = i >> 7, k = i & 127;
            w1t[n * IN_DIM + k] = f2bf(W1[k * HID + n]);
        } else if (b < 96) {
            int i = (b - 64) * 256 + t;         // n*128+k, n<64
            int n = i >> 7, k = i & 127;
            w2t[n * HID + k] = f2bf(W2[k * OUT_DIM + n]);
        } else if (b < 104) {
            int i = (b - 96) * 256 + t;         // j*128+k, j<16
            int j = i >> 7, k = i & 127;
            int hh = j & 7;
            const float* a = (j < 8) ? as1 : ad1;
            float acc = 0.f;
            #pragma unroll
            for (int c = 0; c < C1; ++c)
                acc = fmaf(W1[k * HID + hh * C1 + c], a[hh * C1 + c], acc);
            p1t[j * IN_DIM + k] = f2bf(acc * LOG2E);
        } else {
            int i = (b - 104) * 256 + t;        // j*128+k, j<16
            int j = i >> 7, k = i & 127;
            if (j < 2) {
                const float* a = (j == 0) ? as2 : ad2;
                float acc = 0.f;
                #pragma unroll
                for (int c = 0; c < OUT_DIM; ++c)
                    acc = fmaf(W2[k * OUT_DIM + c], a[c], acc);
                p2t[j * HID + k] = f2bf(acc * LOG2E);
            } else {
                p2t[j * HID + k] = 0;
            }
        }
    }
}

__global__ __launch_bounds__(256) void bucket_scan(
        const int* __restrict__ cnt, int* __restrict__ tileOff /* [NT][NB] */,
        int* __restrict__ bucketStart /* [NB+1] */) {
    __shared__ int s[256];
    int t = threadIdx.x;
    int total = 0;
    if (t < NB) {
        int run = 0;
        for (int k = 0; k < NT; ++k) {
            int c = cnt[k * NB + t];       // coalesced across t
            tileOff[k * NB + t] = run;
            run += c;
        }
        total = run;
    }
    s[t] = total;
    __syncthreads();
    #pragma unroll
    for (int off = 1; off < 256; off <<= 1) {
        int add = (t >= off) ? s[t - off] : 0;
        __syncthreads();
        s[t] += add;
        __syncthreads();
    }
    if (t < NB) bucketStart[t] = s[t] - total;   // exclusive
    if (t == 0) bucketStart[NB] = ET;
}

__global__ __launch_bounds__(256) void bucket_scatter(
        const int* __restrict__ src, const int* __restrict__ dst,
        const int* __restrict__ tileOff, const int* __restrict__ bucketStart,
        int2* __restrict__ pairs) {
    __shared__ int cur[NB];
    int t = threadIdx.x;
    for (int b = t; b < NB; b += 256)
        cur[b] = bucketStart[b] + tileOff[blockIdx.x * NB + b];
    __syncthreads();
    int base = blockIdx.x * TILE;
    #pragma unroll
    for (int it = 0; it < TILE / 256; ++it) {
        int i = base + it * 256 + t;
        if (i < ET) {
            int s, d;
            if (i < E_EDGES) { s = src[i]; d = dst[i]; }
            else             { s = d = i - E_EDGES; }
            int pos = atomicAdd(&cur[d >> 8], 1);
            pairs[pos] = make_int2(s, d);
        }
    }
}

// ---------------- Mega-kernel B: bucket_build + l1_transform_mfma ----------------

__global__ __launch_bounds__(256) void build_l1t(
        const int2* __restrict__ pairs, const int* __restrict__ bucketStart,
        int* __restrict__ row_start, int* __restrict__ csr_src,
        const unsigned short* __restrict__ xb, const unsigned short* __restrict__ w1t,
        const unsigned short* __restrict__ p1t, unsigned short* __restrict__ h1b,
        float* __restrict__ a_src, float* __restrict__ a_dst) {
    __shared__ int sdeg[256];
    __shared__ int sscan[256];
    int t = threadIdx.x;
    if (blockIdx.x < NB) {
        // ---- per-bucket CSR build (LDS atomics only) ----
        int b = blockIdx.x;
        int beg = bucketStart[b], end = bucketStart[b + 1];
        sdeg[t] = 0;
        __syncthreads();
        for (int j = beg + t; j < end; j += 256)
            atomicAdd(&sdeg[pairs[j].y & 255], 1);
        __syncthreads();
        int v = sdeg[t];
        sscan[t] = v;
        __syncthreads();
        #pragma unroll
        for (int off = 1; off < 256; off <<= 1) {
            int add = (t >= off) ? sscan[t - off] : 0;
            __syncthreads();
            sscan[t] += add;
            __syncthreads();
        }
        int pos0 = beg + sscan[t] - v;   // exclusive prefix within bucket
        int n = b * 256 + t;
        if (n < N_NODES) row_start[n] = pos0;
        if (b == 0 && t == 0) row_start[N_NODES] = ET;
        __syncthreads();
        sscan[t] = pos0;                 // reuse as cursor
        __syncthreads();
        for (int j = beg + t; j < end; j += 256) {
            int2 p = pairs[j];
            int pos = atomicAdd(&sscan[p.y & 255], 1);
            csr_src[pos] = p.x;
        }
        return;
    }
    // ---- layer-1 transform via MFMA, LDS-free ----
    int bb = blockIdx.x - NB;
    int w = t >> 6, lane = t & 63;
    int l15 = lane & 15, quad = lane >> 4;
    int n0 = bb * 64 + w * 16;
    int mrow = n0 + l15;
    int mload = (mrow < N_NODES) ? mrow : (N_NODES - 1);

    bf16x8 af[4];
    #pragma unroll
    for (int s = 0; s < 4; ++s)
        af[s] = *(const bf16x8*)&xb[(size_t)mload * IN_DIM + s * 32 + quad * 8];

    #pragma unroll
    for (int tt = 0; tt < 9; ++tt) {
        const unsigned short* Brow = (tt < 8) ? &w1t[(tt * 16 + l15) * IN_DIM]
                                              : &p1t[l15 * IN_DIM];
        f32x4 acc = {0.f, 0.f, 0.f, 0.f};
        #pragma unroll
        for (int s = 0; s < 4; ++s) {
            bf16x8 bf = *(const bf16x8*)&Brow[s * 32 + quad * 8];
            acc = __builtin_amdgcn_mfma_f32_16x16x32_bf16(af[s], bf, acc, 0, 0, 0);
        }
        int nodeb = n0 + quad * 4;
        if (tt < 8) {
            int ch = tt * 16 + l15;
            #pragma unroll
            for (int r = 0; r < 4; ++r)
                if (nodeb + r < N_NODES)
                    h1b[(size_t)(nodeb + r) * HID + ch] = f2bf(acc[r]);
        } else {
            #pragma unroll
            for (int r = 0; r < 4; ++r) {
                if (nodeb + r < N_NODES) {
                    if (l15 < 8) a_src[(nodeb + r) * HEADS + l15] = acc[r];
                    else         a_dst[(nodeb + r) * HEADS + (l15 - 8)] = acc[r];
                }
            }
        }
    }
}

// ---------------- Layer 1: aggregate (exp2 softmax, unroll x8) ----------------

__global__ __launch_bounds__(128) void l1_aggregate(
        const unsigned short* __restrict__ h1b, const float* __restrict__ a_src,
        const float* __restrict__ a_dst, const int* __restrict__ row_start,
        const int* __restrict__ csr_src, const float* __restrict__ b1,
        unsigned short* __restrict__ h_act_b) {
    int w = threadIdx.x >> 6;
    int lane = threadIdx.x & 63;
    int n = blockIdx.x * 2 + w;
    int c0 = lane * 2;
    int h = lane >> 3;
    int beg = row_start[n], end = row_start[n + 1];
    float adst = a_dst[n * HEADS + h];
    float l = 0.f, accx = 0.f, accy = 0.f;

    auto update = [&](float e, uint32 u) {
        float vx = __uint_as_float(u << 16);
        float vy = __uint_as_float(u & 0xFFFF0000u);
        e += adst;
        e = fmaxf(e, NEG_SLOPE * e);          // leaky relu (log2-scaled domain)
        float p = exp2f(e);                   // a's pre-scaled by log2(e)
        l += p;
        accx = fmaf(p, vx, accx);
        accy = fmaf(p, vy, accy);
    };

    int j = beg;
    for (; j + 8 <= end; j += 8) {
        int ss[8];
        #pragma unroll
        for (int q = 0; q < 8; ++q) ss[q] = csr_src[j + q];
        float ee[8]; uint32 uu[8];
        #pragma unroll
        for (int q = 0; q < 8; ++q) ee[q] = a_src[ss[q] * HEADS + h];
        #pragma unroll
        for (int q = 0; q < 8; ++q) uu[q] = *(const uint32*)&h1b[(size_t)ss[q] * HID + c0];
        #pragma unroll
        for (int q = 0; q < 8; ++q) update(ee[q], uu[q]);
    }
    for (; j + 4 <= end; j += 4) {
        int ss[4];
        #pragma unroll
        for (int q = 0; q < 4; ++q) ss[q] = csr_src[j + q];
        float ee[4]; uint32 uu[4];
        #pragma unroll
        for (int q = 0; q < 4; ++q) ee[q] = a_src[ss[q] * HEADS + h];
        #pragma unroll
        for (int q = 0; q < 4; ++q) uu[q] = *(const uint32*)&h1b[(size_t)ss[q] * HID + c0];
        #pragma unroll
        for (int q = 0; q < 4; ++q) update(ee[q], uu[q]);
    }
    for (; j < end; ++j) {
        int s = csr_src[j];
        float e = a_src[s * HEADS + h];
        uint32 u = *(const uint32*)&h1b[(size_t)s * HID + c0];
        update(e, u);
    }

    float inv = 1.f / (l + 1e-16f);
    float vx = accx * inv + b1[c0];
    float vy = accy * inv + b1[c0 + 1];
    vx = vx > 0.f ? vx : (__expf(vx) - 1.f);   // ELU
    vy = vy > 0.f ? vy : (__expf(vy) - 1.f);
    uint32 packed = (uint32)f2bf(vx) | ((uint32)f2bf(vy) << 16);
    *(uint32*)&h_act_b[(size_t)n * HID + c0] = packed;
}

// ---------------- Layer 2: transform via MFMA, LDS-free ----------------

__global__ __launch_bounds__(256) void l2_transform_mfma(
        const unsigned short* __restrict__ h_act_b, const unsigned short* __restrict__ w2t,
        const unsigned short* __restrict__ p2t, unsigned short* __restrict__ h2b,
        float* __restrict__ a_src2, float* __restrict__ a_dst2) {
    int t = threadIdx.x, w = t >> 6, lane = t & 63;
    int l15 = lane & 15, quad = lane >> 4;
    int n0 = blockIdx.x * 64 + w * 16;
    int mrow = n0 + l15;
    int mload = (mrow < N_NODES) ? mrow : (N_NODES - 1);

    bf16x8 af[4];
    #pragma unroll
    for (int s = 0; s < 4; ++s)
        af[s] = *(const bf16x8*)&h_act_b[(size_t)mload * HID + s * 32 + quad * 8];

    #pragma unroll
    for (int tt = 0; tt < 5; ++tt) {
        const unsigned short* Brow = (tt < 4) ? &w2t[(tt * 16 + l15) * HID]
                                              : &p2t[l15 * HID];
        f32x4 acc = {0.f, 0.f, 0.f, 0.f};
        #pragma unroll
        for (int s = 0; s < 4; ++s) {
            bf16x8 bf = *(const bf16x8*)&Brow[s * 32 + quad * 8];
            acc = __builtin_amdgcn_mfma_f32_16x16x32_bf16(af[s], bf, acc, 0, 0, 0);
        }
        int nodeb = n0 + quad * 4;
        if (tt < 4) {
            int ch = tt * 16 + l15;
            #pragma unroll
            for (int r = 0; r < 4; ++r)
                if (nodeb + r < N_NODES)
                    h2b[(size_t)(nodeb + r) * OUT_DIM + ch] = f2bf(acc[r]);
        } else {
            #pragma unroll
            for (int r = 0; r < 4; ++r) {
                if (nodeb + r < N_NODES) {
                    if (l15 == 0) a_src2[nodeb + r] = acc[r];
                    else if (l15 == 1) a_dst2[nodeb + r] = acc[r];
                }
            }
        }
    }
}

// ---------------- Layer 2: aggregate + log_softmax (unroll x8) ----------------

__global__ __launch_bounds__(128) void l2_aggregate(
        const unsigned short* __restrict__ h2b, const float* __restrict__ a_src2,
        const float* __restrict__ a_dst2, const int* __restrict__ row_start,
        const int* __restrict__ csr_src, const float* __restrict__ b2,
        float* __restrict__ out) {
    int w = threadIdx.x >> 6;
    int lane = threadIdx.x & 63;
    int n = blockIdx.x * 2 + w;
    int beg = row_start[n], end = row_start[n + 1];
    float adst = a_dst2[n];
    float l = 0.f, acc = 0.f;

    auto update = [&](float e, unsigned short us) {
        float v = __uint_as_float(((uint32)us) << 16);
        e += adst;
        e = fmaxf(e, NEG_SLOPE * e);
        float p = exp2f(e);                   // a's pre-scaled by log2(e)
        l += p;
        acc = fmaf(p, v, acc);
    };

    int j = beg;
    for (; j + 8 <= end; j += 8) {
        int ss[8];
        #pragma unroll
        for (int q = 0; q < 8; ++q) ss[q] = csr_src[j + q];
        float ee[8]; unsigned short vv[8];
        #pragma unroll
        for (int q = 0; q < 8; ++q) ee[q] = a_src2[ss[q]];
        #pragma unroll
        for (int q = 0; q < 8; ++q) vv[q] = h2b[(size_t)ss[q] * OUT_DIM + lane];
        #pragma unroll
        for (int q = 0; q < 8; ++q) update(ee[q], vv[q]);
    }
    for (; j + 4 <= end; j += 4) {
        int ss[4];
        #pragma unroll
        for (int q = 0; q < 4; ++q) ss[q] = csr_src[j + q];
        float ee[4]; unsigned short vv[4];
        #pragma unroll
        for (int q = 0; q < 4; ++q) ee[q] = a_src2[ss[q]];
        #pragma unroll
        for (int q = 0; q < 4; ++q) vv[q] = h2b[(size_t)ss[q] * OUT_DIM + lane];
        #pragma unroll
        for (int q = 0; q < 4; ++q) update(ee[q], vv[q]);
    }
    for (; j < end; ++j) {
        int s = csr_src[j];
        update(a_src2[s], h2b[(size_t)s * OUT_DIM + lane]);
    }

    float o = acc / (l + 1e-16f) + b2[lane];
    // log_softmax over 64 channels (one wave)
    float mx = o;
    #pragma unroll
    for (int ww = 32; ww > 0; ww >>= 1) mx = fmaxf(mx, __shfl_xor(mx, ww, 64));
    float ex = __expf(o - mx);
    float ssum = ex;
    #pragma unroll
    for (int ww = 32; ww > 0; ww >>= 1) ssum += __shfl_xor(ssum, ww, 64);
    out[(size_t)n * OUT_DIM + lane] = o - mx - __logf(ssum);
}

// ---------------- launch ----------------

extern "C" void kernel_launch(void* const* d_in, const int* in_sizes, int n_in,
                              void* d_out, int out_size, void* d_ws, size_t ws_size,
                              hipStream_t stream) {
    const float* x   = (const float*)d_in[0];
    const int*   ei  = (const int*)d_in[1];
    const float* W1  = (const float*)d_in[2];
    const float* as1 = (const float*)d_in[3];
    const float* ad1 = (const float*)d_in[4];
    const float* b1  = (const float*)d_in[5];
    const float* W2  = (const float*)d_in[6];
    const float* as2 = (const float*)d_in[7];
    const float* ad2 = (const float*)d_in[8];
    const float* b2  = (const float*)d_in[9];
    float* out = (float*)d_out;

    const int* src = ei;             // row 0
    const int* dst = ei + E_EDGES;   // row 1

    char* ws = (char*)d_ws;
    size_t off = 0;
    auto alloc = [&](size_t bytes) -> void* {
        void* p = ws + off;
        off += (bytes + 255) & ~size_t(255);
        return p;
    };
    unsigned short* xb     = (unsigned short*)alloc((size_t)N_NODES * IN_DIM * 2);
    unsigned short* h1b    = (unsigned short*)alloc((size_t)N_NODES * HID * 2);
    unsigned short* h_act_b= (unsigned short*)alloc((size_t)N_NODES * HID * 2);
    unsigned short* h2b    = (unsigned short*)alloc((size_t)N_NODES * OUT_DIM * 2);
    unsigned short* w1t    = (unsigned short*)alloc((size_t)HID * IN_DIM * 2);
    unsigned short* p1t    = (unsigned short*)alloc((size_t)16 * IN_DIM * 2);
    unsigned short* w2t    = (unsigned short*)alloc((size_t)OUT_DIM * HID * 2);
    unsigned short* p2t    = (unsigned short*)alloc((size_t)16 * HID * 2);
    float* a_src1    = (float*)alloc((size_t)N_NODES * HEADS * 4);
    float* a_dst1    = (float*)alloc((size_t)N_NODES * HEADS * 4);
    float* a_src2    = (float*)alloc((size_t)N_NODES * 4);
    float* a_dst2    = (float*)alloc((size_t)N_NODES * 4);
    int*   row_start = (int*)alloc((size_t)(N_NODES + 1) * 4);
    int*   csr_src   = (int*)alloc((size_t)ET * 4);
    int2*  pairs     = (int2*)alloc((size_t)ET * 8);
    int*   cnt       = (int*)alloc((size_t)NB * NT * 4);
    int*   tileOff   = (int*)alloc((size_t)NB * NT * 4);
    int*   bucketStart = (int*)alloc((size_t)(NB + 1) * 4);

    prep_all<<<MEGA_A, 256, 0, stream>>>(dst, cnt, x, xb, W1, as1, ad1,
                                         W2, as2, ad2, w1t, p1t, w2t, p2t);
    bucket_scan<<<1, 256, 0, stream>>>(cnt, tileOff, bucketStart);
    bucket_scatter<<<NT, 256, 0, stream>>>(src, dst, tileOff, bucketStart, pairs);
    build_l1t<<<MEGA_B, 256, 0, stream>>>(pairs, bucketStart, row_start, csr_src,
                                          xb, w1t, p1t, h1b, a_src1, a_dst1);
    l1_aggregate<<<N_NODES / 2, 128, 0, stream>>>(h1b, a_src1, a_dst1, row_start, csr_src, b1, h_act_b);
    l2_transform_mfma<<<L1T_BLOCKS, 256, 0, stream>>>(h_act_b, w2t, p2t, h2b, a_src2, a_dst2);
    l2_aggregate<<<N_NODES / 2, 128, 0, stream>>>(h2b, a_src2, a_dst2, row_start, csr_src, b2, out);
}